// Round 3
// baseline (862.858 us; speedup 1.0000x reference)
//
#include <hip/hip_runtime.h>
#include <hip/hip_cooperative_groups.h>

namespace cg = cooperative_groups;

#define HID    128
#define NTREES 8
#define DEPTH  15
#define TNODES 32767
#define TM     32
#define FUSE_TOP 10   // levels FUSE_TOP..0 run in one cooperative kernel (256 blocks)

typedef __attribute__((ext_vector_type(8))) short bfrag8;   // 8 bf16 = 4 VGPR
typedef __attribute__((ext_vector_type(4))) float facc4;    // MFMA C/D
typedef __attribute__((ext_vector_type(4))) unsigned int u32x4;

__device__ __forceinline__ unsigned short f2b(float x) {
  union { float f; unsigned u; } a; a.f = x;
  unsigned r = a.u + 0x7fffu + ((a.u >> 16) & 1u);   // RNE
  return (unsigned short)(r >> 16);
}
__device__ __forceinline__ float b2f(unsigned short b) {
  union { float f; unsigned u; } a; a.u = ((unsigned)b) << 16;
  return a.f;
}
__device__ __forceinline__ float fast_sigmoid(float x) {
  return __builtin_amdgcn_rcpf(1.0f + __expf(-x));
}
__device__ __forceinline__ float fast_tanh(float x) {
  return 1.0f - 2.0f * __builtin_amdgcn_rcpf(1.0f + __expf(2.0f * x));
}
__device__ __forceinline__ void store8(char* base, int byte, const float* v, float sc) {
  union { unsigned short us[8]; u32x4 q; } p;
  #pragma unroll
  for (int i = 0; i < 8; ++i) p.us[i] = f2b(v[i] * sc);
  *(u32x4*)(base + byte) = p.q;
}

// Transpose+convert weights to bf16 [N][K] (k-contiguous) for MFMA B-fragments.
__global__ void prep_weights(const float* __restrict__ W_iou,
                             const float* __restrict__ U_iou,
                             const float* __restrict__ U_f_w,
                             unsigned short* __restrict__ Wt,
                             unsigned short* __restrict__ Ut,
                             unsigned short* __restrict__ Uft) {
  int i = blockIdx.x * 256 + threadIdx.x;
  if (i < 384 * HID) {
    int n = i >> 7, k = i & 127;
    Wt[i] = f2b(W_iou[k * 384 + n]);
    Ut[i] = f2b(U_iou[k * 384 + n]);
  }
  if (i < HID * HID) {
    int n = i >> 7, k = i & 127;
    Uft[i] = f2b(U_f_w[k * HID + n]);
  }
}

// ---------------- leaf level: LDS-free, direct-gather A, prefetched c_init ----
// 512 thr = 8 waves; wave w owns d in [16w,16w+16); block = 32 tree-nodes.
__global__ __launch_bounds__(512, 5)
void leaf_kernel(const int* __restrict__ wordid,
                 const int* __restrict__ mask,
                 const float* __restrict__ c_init,
                 const float* __restrict__ emb_table,
                 const unsigned short* __restrict__ Wt,
                 const float* __restrict__ b_iou,
                 float* __restrict__ h_out,
                 float* __restrict__ c_cur)
{
  const int tid = threadIdx.x;
  const int lane = tid & 63, w = tid >> 6;
  const int lrow = lane & 15, lgrp = lane >> 4;
  const int r0 = blockIdx.x * TM;
  const int level = DEPTH - 1;
  const int nl = 1 << level, ps = nl - 1;
  const int d = w * 16 + lrow;

  // prefetch c_init for this lane's 8 outputs (independent of everything below)
  float ci[2][4];
  #pragma unroll
  for (int rt = 0; rt < 2; ++rt)
    #pragma unroll
    for (int reg = 0; reg < 4; ++reg) {
      int r = r0 + rt * 16 + 4 * lgrp + reg;
      size_t gn = (size_t)(r >> level) * TNODES + ps + (r & (nl - 1));
      ci[rt][reg] = c_init[gn * HID + d];
    }

  int idxA[2]; float mfA[2];
  #pragma unroll
  for (int rt = 0; rt < 2; ++rt) {
    int r = r0 + rt * 16 + lrow;
    size_t gn = (size_t)(r >> level) * TNODES + ps + (r & (nl - 1));
    int mk = mask[gn];
    idxA[rt] = wordid[gn] * mk;
    mfA[rt] = (float)mk;
  }

  facc4 acc[2][3];
  #pragma unroll
  for (int rt = 0; rt < 2; ++rt)
    #pragma unroll
    for (int g = 0; g < 3; ++g)
      #pragma unroll
      for (int e = 0; e < 4; ++e) acc[rt][g][e] = 0.f;

  #pragma unroll
  for (int k = 0; k < 4; ++k) {
    bfrag8 af[2];
    #pragma unroll
    for (int rt = 0; rt < 2; ++rt) {
      const float* src = emb_table + (size_t)idxA[rt] * HID + k * 32 + lgrp * 8;
      float v[8];
      *(float4*)(v)     = *(const float4*)(src);
      *(float4*)(v + 4) = *(const float4*)(src + 4);
      union { unsigned short us[8]; bfrag8 b; } p;
      #pragma unroll
      for (int i = 0; i < 8; ++i) p.us[i] = f2b(v[i] * mfA[rt]);
      af[rt] = p.b;
    }
    #pragma unroll
    for (int g = 0; g < 3; ++g) {
      bfrag8 bf = *(const bfrag8*)(Wt + (size_t)((g * 8 + w) * 16 + lrow) * HID + k * 32 + lgrp * 8);
      acc[0][g] = __builtin_amdgcn_mfma_f32_16x16x32_bf16(af[0], bf, acc[0][g], 0, 0, 0);
      acc[1][g] = __builtin_amdgcn_mfma_f32_16x16x32_bf16(af[1], bf, acc[1][g], 0, 0, 0);
    }
  }

  const float bi = b_iou[d], bo = b_iou[HID + d], bu = b_iou[2 * HID + d];
  #pragma unroll
  for (int rt = 0; rt < 2; ++rt)
    #pragma unroll
    for (int reg = 0; reg < 4; ++reg) {
      int m = rt * 16 + 4 * lgrp + reg;
      int r = r0 + m;
      size_t gn = (size_t)(r >> level) * TNODES + ps + (r & (nl - 1));
      float iv = acc[rt][0][reg] + bi;
      float ov = acc[rt][1][reg] + bo;
      float uv = acc[rt][2][reg] + bu;
      float cn = fmaf(fast_sigmoid(iv), fast_tanh(uv), ci[rt][reg]);
      float hn = fast_sigmoid(ov) * fast_tanh(cn);
      c_cur[(size_t)r * HID + d] = cn;
      h_out[gn * HID + d] = hn;
    }
}

// ---------------- non-leaf level body (shared by standalone + fused) ---------
// LDS: htild bf16 [32][128] swizzled @0 (8K); hch bf16 [64][128] swizzled @8K
// (16K); f bf16 [64][128] overlays hch after the f-GEMM. Two barriers total.
__device__ __forceinline__ void nonleaf_body(
    int level, int r0,
    const int* __restrict__ wordid, const int* __restrict__ mask,
    const float* __restrict__ emb_table,
    const unsigned short* __restrict__ Wt, const unsigned short* __restrict__ Ut,
    const unsigned short* __restrict__ Uft,
    const float* __restrict__ b_iou, const float* __restrict__ U_f_b,
    float* __restrict__ h_out, const float* __restrict__ c_prev,
    float* __restrict__ c_cur, char* smem)
{
  const int tid = threadIdx.x;
  const int lane = tid & 63, w = tid >> 6;
  const int lrow = lane & 15, lgrp = lane >> 4;
  const int nl = 1 << level, ps = nl - 1;
  const int R = NTREES << level;
  const int d = w * 16 + lrow;

  // stage children h (64 rows) -> LDS @8192, bf16 swizzled
  for (int s = tid; s < 64 * 16; s += 512) {
    int row = s >> 4, sl = s & 15;
    int r = r0 + (row >> 1); if (r >= R) r = R - 1;
    int tree = r >> level, j = r & (nl - 1);
    size_t gch = (size_t)tree * TNODES + 2 * (ps + j) + 1 + (row & 1);
    const float* src = h_out + gch * HID + sl * 8;
    float v[8];
    *(float4*)(v)     = *(const float4*)(src);
    *(float4*)(v + 4) = *(const float4*)(src + 4);
    int byte = 8192 + ((row * 256 + sl * 16) ^ ((row & 7) << 4));
    store8(smem, byte, v, 1.0f);
  }
  // htild (32 rows) -> LDS @0 = child0 + child1 (global re-read, L1/L2-hot)
  for (int s = tid; s < 32 * 16; s += 512) {
    int m = s >> 4, sl = s & 15;
    int r = r0 + m; if (r >= R) r = R - 1;
    int tree = r >> level, j = r & (nl - 1);
    size_t gl = (size_t)tree * TNODES + 2 * (ps + j) + 1;
    const float* s0 = h_out + gl * HID + sl * 8;
    float v[8], u[8];
    *(float4*)(v)     = *(const float4*)(s0);
    *(float4*)(v + 4) = *(const float4*)(s0 + 4);
    *(float4*)(u)     = *(const float4*)(s0 + HID);
    *(float4*)(u + 4) = *(const float4*)(s0 + HID + 4);
    #pragma unroll
    for (int i = 0; i < 8; ++i) v[i] += u[i];
    int byte = (m * 256 + sl * 16) ^ ((m & 7) << 4);
    store8(smem, byte, v, 1.0f);
  }

  // prefetch c_prev for this lane's outputs; latency hidden under both GEMMs
  float cp0[2][4], cp1[2][4];
  #pragma unroll
  for (int rt = 0; rt < 2; ++rt)
    #pragma unroll
    for (int reg = 0; reg < 4; ++reg) {
      int r = r0 + rt * 16 + 4 * lgrp + reg; if (r >= R) r = R - 1;
      int tree = r >> level, j = r & (nl - 1);
      size_t cpl = ((size_t)tree << (level + 1)) | (size_t)(j << 1);
      cp0[rt][reg] = c_prev[cpl * HID + d];
      cp1[rt][reg] = c_prev[(cpl + 1) * HID + d];
    }

  __syncthreads();

  // f-GEMM (children @8192); wave w covers f cols [16w,16w+16)
  facc4 accf[4];
  #pragma unroll
  for (int rt = 0; rt < 4; ++rt)
    #pragma unroll
    for (int e = 0; e < 4; ++e) accf[rt][e] = 0.f;
  #pragma unroll
  for (int k = 0; k < 4; ++k) {
    bfrag8 bf = *(const bfrag8*)(Uft + (size_t)(w * 16 + lrow) * HID + k * 32 + lgrp * 8);
    #pragma unroll
    for (int rt = 0; rt < 4; ++rt) {
      int row = rt * 16 + lrow;
      bfrag8 af = *(const bfrag8*)(smem + 8192 + ((row * 256 + k * 64 + lgrp * 16) ^ ((row & 7) << 4)));
      accf[rt] = __builtin_amdgcn_mfma_f32_16x16x32_bf16(af, bf, accf[rt], 0, 0, 0);
    }
  }
  __syncthreads();   // all hch reads done -> overlay f
  {
    unsigned short* fsw = (unsigned short*)(smem + 8192);
    float fb = U_f_b[d];
    #pragma unroll
    for (int rt = 0; rt < 4; ++rt)
      #pragma unroll
      for (int reg = 0; reg < 4; ++reg) {
        int frow = rt * 16 + 4 * lgrp + reg;
        fsw[frow * HID + d] = f2b(fast_sigmoid(accf[rt][reg] + fb));
      }
  }

  // iou GEMM: emb direct-gather + htild from LDS; wave w cols g*128 + [16w,16w+16)
  int idxA[2]; float mfA[2];
  #pragma unroll
  for (int rt = 0; rt < 2; ++rt) {
    int r = r0 + rt * 16 + lrow; if (r >= R) r = R - 1;
    size_t gn = (size_t)(r >> level) * TNODES + ps + (r & (nl - 1));
    int mk = mask[gn];
    idxA[rt] = wordid[gn] * mk;
    mfA[rt] = (float)mk;
  }
  facc4 acc[2][3];
  #pragma unroll
  for (int rt = 0; rt < 2; ++rt)
    #pragma unroll
    for (int g = 0; g < 3; ++g)
      #pragma unroll
      for (int e = 0; e < 4; ++e) acc[rt][g][e] = 0.f;

  #pragma unroll
  for (int k = 0; k < 4; ++k) {   // op 0: emb @ Wt
    bfrag8 af[2];
    #pragma unroll
    for (int rt = 0; rt < 2; ++rt) {
      const float* src = emb_table + (size_t)idxA[rt] * HID + k * 32 + lgrp * 8;
      float v[8];
      *(float4*)(v)     = *(const float4*)(src);
      *(float4*)(v + 4) = *(const float4*)(src + 4);
      union { unsigned short us[8]; bfrag8 b; } p;
      #pragma unroll
      for (int i = 0; i < 8; ++i) p.us[i] = f2b(v[i] * mfA[rt]);
      af[rt] = p.b;
    }
    #pragma unroll
    for (int g = 0; g < 3; ++g) {
      bfrag8 bf = *(const bfrag8*)(Wt + (size_t)((g * 8 + w) * 16 + lrow) * HID + k * 32 + lgrp * 8);
      acc[0][g] = __builtin_amdgcn_mfma_f32_16x16x32_bf16(af[0], bf, acc[0][g], 0, 0, 0);
      acc[1][g] = __builtin_amdgcn_mfma_f32_16x16x32_bf16(af[1], bf, acc[1][g], 0, 0, 0);
    }
  }
  #pragma unroll
  for (int k = 0; k < 4; ++k) {   // op 1: htild @ Ut
    bfrag8 af[2];
    #pragma unroll
    for (int rt = 0; rt < 2; ++rt) {
      int row = rt * 16 + lrow;
      af[rt] = *(const bfrag8*)(smem + ((row * 256 + k * 64 + lgrp * 16) ^ ((row & 7) << 4)));
    }
    #pragma unroll
    for (int g = 0; g < 3; ++g) {
      bfrag8 bf = *(const bfrag8*)(Ut + (size_t)((g * 8 + w) * 16 + lrow) * HID + k * 32 + lgrp * 8);
      acc[0][g] = __builtin_amdgcn_mfma_f32_16x16x32_bf16(af[0], bf, acc[0][g], 0, 0, 0);
      acc[1][g] = __builtin_amdgcn_mfma_f32_16x16x32_bf16(af[1], bf, acc[1][g], 0, 0, 0);
    }
  }

  // epilogue: f rows needed are at this wave's own d-slice (same-wave LDS,
  // ds ops in program order -> no extra barrier needed)
  const unsigned short* fsr = (const unsigned short*)(smem + 8192);
  const float bi = b_iou[d], bo = b_iou[HID + d], bu = b_iou[2 * HID + d];
  #pragma unroll
  for (int rt = 0; rt < 2; ++rt)
    #pragma unroll
    for (int reg = 0; reg < 4; ++reg) {
      int m = rt * 16 + 4 * lgrp + reg;
      int r = r0 + m;
      if (r >= R) continue;
      int tree = r >> level, j = r & (nl - 1);
      size_t gn = (size_t)tree * TNODES + ps + j;
      float iv = acc[rt][0][reg] + bi;
      float ov = acc[rt][1][reg] + bo;
      float uv = acc[rt][2][reg] + bu;
      float cin = b2f(fsr[(2 * m) * HID + d])     * cp0[rt][reg]
                + b2f(fsr[(2 * m + 1) * HID + d]) * cp1[rt][reg];
      float cn = fmaf(fast_sigmoid(iv), fast_tanh(uv), cin);
      float hn = fast_sigmoid(ov) * fast_tanh(cn);
      c_cur[(size_t)r * HID + d] = cn;
      h_out[gn * HID + d] = hn;
      if (gn == 0) h_out[(size_t)NTREES * TNODES * HID + d] = hn;  // h_all[0] tail
    }
}

__global__ __launch_bounds__(512, 4)
void nonleaf_kernel(int level,
                    const int* __restrict__ wordid, const int* __restrict__ mask,
                    const float* __restrict__ emb_table,
                    const unsigned short* __restrict__ Wt, const unsigned short* __restrict__ Ut,
                    const unsigned short* __restrict__ Uft,
                    const float* __restrict__ b_iou, const float* __restrict__ U_f_b,
                    float* __restrict__ h_out, const float* __restrict__ c_prev,
                    float* __restrict__ c_cur)
{
  __shared__ __align__(16) char smem[24576];
  nonleaf_body(level, blockIdx.x * TM, wordid, mask, emb_table, Wt, Ut, Uft,
               b_iou, U_f_b, h_out, c_prev, c_cur, smem);
}

// levels FUSE_TOP..0 in one cooperative launch (256 blocks -> 1/CU, co-resident)
__global__ __launch_bounds__(512, 4)
void fused_tail_kernel(const int* __restrict__ wordid, const int* __restrict__ mask,
                       const float* __restrict__ emb_table,
                       const unsigned short* __restrict__ Wt, const unsigned short* __restrict__ Ut,
                       const unsigned short* __restrict__ Uft,
                       const float* __restrict__ b_iou, const float* __restrict__ U_f_b,
                       float* __restrict__ h_out, float* __restrict__ bufA, float* __restrict__ bufB)
{
  __shared__ __align__(16) char smem[24576];
  cg::grid_group grid = cg::this_grid();
  for (int l = FUSE_TOP; l >= 0; --l) {
    int nb = (NTREES << l) / TM; if (nb < 1) nb = 1;
    if ((int)blockIdx.x < nb) {
      float* ccur = (l & 1) ? bufB : bufA;
      const float* cprev = (l & 1) ? bufA : bufB;
      nonleaf_body(l, blockIdx.x * TM, wordid, mask, emb_table, Wt, Ut, Uft,
                   b_iou, U_f_b, h_out, cprev, ccur, smem);
    }
    grid.sync();
  }
}

extern "C" void kernel_launch(void* const* d_in, const int* in_sizes, int n_in,
                              void* d_out, int out_size, void* d_ws, size_t ws_size,
                              hipStream_t stream) {
  const int*   wordid = (const int*)d_in[0];
  const int*   mask   = (const int*)d_in[1];
  const float* c_init = (const float*)d_in[3];
  const float* emb    = (const float*)d_in[4];
  const float* W_iou  = (const float*)d_in[5];
  const float* U_iou  = (const float*)d_in[6];
  const float* b_iou  = (const float*)d_in[7];
  const float* U_f_w  = (const float*)d_in[8];
  const float* U_f_b  = (const float*)d_in[9];
  float* out = (float*)d_out;

  char* ws = (char*)d_ws;
  const unsigned short* Wt  = (const unsigned short*)(ws);
  const unsigned short* Ut  = (const unsigned short*)(ws + 98304);
  const unsigned short* Uft = (const unsigned short*)(ws + 196608);
  float* bufA = (float*)(ws + 262144);               // even levels' c (max 67.1 MB)
  float* bufB = (float*)(ws + 262144 + 67108864);    // odd levels' c  (max 33.6 MB)

  prep_weights<<<192, 256, 0, stream>>>(W_iou, U_iou, U_f_w,
                                        (unsigned short*)Wt, (unsigned short*)Ut,
                                        (unsigned short*)Uft);

  leaf_kernel<<<(NTREES << (DEPTH - 1)) / TM, 512, 0, stream>>>(
      wordid, mask, c_init, emb, Wt, b_iou, out, bufA);

  for (int l = DEPTH - 2; l > FUSE_TOP; --l) {
    int blocks = (NTREES << l) / TM;
    float* ccur = (l & 1) ? bufB : bufA;
    const float* cprev = (l & 1) ? bufA : bufB;
    nonleaf_kernel<<<blocks, 512, 0, stream>>>(l, wordid, mask, emb, Wt, Ut, Uft,
                                               b_iou, U_f_b, out, cprev, ccur);
  }

  void* args[] = {(void*)&wordid, (void*)&mask, (void*)&emb, (void*)&Wt, (void*)&Ut,
                  (void*)&Uft, (void*)&b_iou, (void*)&U_f_b, (void*)&out,
                  (void*)&bufA, (void*)&bufB};
  hipError_t e = hipLaunchCooperativeKernel(reinterpret_cast<void*>(fused_tail_kernel),
                                            dim3(256), dim3(512), args, 0, stream);
  if (e != hipSuccess) {
    // fallback: per-level launches (known-good path)
    for (int l = FUSE_TOP; l >= 0; --l) {
      int blocks = (NTREES << l) / TM; if (blocks < 1) blocks = 1;
      float* ccur = (l & 1) ? bufB : bufA;
      const float* cprev = (l & 1) ? bufA : bufB;
      nonleaf_kernel<<<blocks, 512, 0, stream>>>(l, wordid, mask, emb, Wt, Ut, Uft,
                                                 b_iou, U_f_b, out, cprev, ccur);
    }
  }
}

// Round 4
// 660.285 us; speedup vs baseline: 1.3068x; 1.3068x over previous
//
#include <hip/hip_runtime.h>

#define HID    128
#define NTREES 8
#define DEPTH  15
#define TNODES 32767
#define TM     32
#define VOCAB  32000

typedef __attribute__((ext_vector_type(8))) short bfrag8;   // 8 bf16 = 4 VGPR
typedef __attribute__((ext_vector_type(4))) float facc4;    // MFMA C/D
typedef __attribute__((ext_vector_type(4))) unsigned int u32x4;

union U8 { u32x4 q; bfrag8 b; };

__device__ __forceinline__ unsigned short f2b(float x) {
  union { float f; unsigned u; } a; a.f = x;
  unsigned r = a.u + 0x7fffu + ((a.u >> 16) & 1u);   // RNE
  return (unsigned short)(r >> 16);
}
__device__ __forceinline__ float b2f(unsigned short b) {
  union { float f; unsigned u; } a; a.u = ((unsigned)b) << 16;
  return a.f;
}
__device__ __forceinline__ float fast_sigmoid(float x) {
  return __builtin_amdgcn_rcpf(1.0f + __expf(-x));
}
__device__ __forceinline__ float fast_tanh(float x) {
  return 1.0f - 2.0f * __builtin_amdgcn_rcpf(1.0f + __expf(2.0f * x));
}

// bf16-convert weights (transposed [N][K]) and the whole emb table.
__global__ void prep_kernel(const float* __restrict__ W_iou,
                            const float* __restrict__ U_iou,
                            const float* __restrict__ U_f_w,
                            const float* __restrict__ emb,
                            unsigned short* __restrict__ Wt,
                            unsigned short* __restrict__ Ut,
                            unsigned short* __restrict__ Uft,
                            unsigned short* __restrict__ emb_b) {
  int i = blockIdx.x * 256 + threadIdx.x;
  if (i < 384 * HID) {
    int n = i >> 7, k = i & 127;
    Wt[i] = f2b(W_iou[k * 384 + n]);
    Ut[i] = f2b(U_iou[k * 384 + n]);
  }
  if (i < HID * HID) {
    int n = i >> 7, k = i & 127;
    Uft[i] = f2b(U_f_w[k * HID + n]);
  }
  for (int j = i; j < VOCAB * HID; j += gridDim.x * 256) emb_b[j] = f2b(emb[j]);
}

// ---- leaf (level 14): LDS-free, zero barriers. 512 thr; wave w owns d in [16w,16w+16).
__global__ __launch_bounds__(512, 7)
void leaf_kernel(const int* __restrict__ wordid, const int* __restrict__ mask,
                 const float* __restrict__ c_init,
                 const unsigned short* __restrict__ emb_b,
                 const unsigned short* __restrict__ Wt,
                 const float* __restrict__ b_iou,
                 float* __restrict__ h_out, unsigned short* __restrict__ h_b,
                 unsigned short* __restrict__ c_b) {
  const int tid = threadIdx.x, lane = tid & 63, w = tid >> 6;
  const int lrow = lane & 15, lgrp = lane >> 4;
  int nb = gridDim.x, b = blockIdx.x;
  if ((nb & 7) == 0) { int q = nb >> 3; b = (b & 7) * q + (b >> 3); }  // XCD chunking
  const int r0 = b * TM;
  const int level = DEPTH - 1, nl = 1 << level;
  const int d = w * 16 + lrow;

  int idxA[2]; unsigned mbA[2];
  #pragma unroll
  for (int rt = 0; rt < 2; ++rt) {
    int r = r0 + rt * 16 + lrow;
    size_t gn = (size_t)(r >> level) * TNODES + (nl - 1) + (r & (nl - 1));
    int mk = mask[gn];
    idxA[rt] = wordid[gn] * mk;
    mbA[rt] = mk ? 0xFFFFFFFFu : 0u;
  }
  float ci[2][4];
  #pragma unroll
  for (int rt = 0; rt < 2; ++rt)
    #pragma unroll
    for (int reg = 0; reg < 4; ++reg) {
      int r = r0 + rt * 16 + 4 * lgrp + reg;
      size_t gn = (size_t)(r >> level) * TNODES + (nl - 1) + (r & (nl - 1));
      ci[rt][reg] = c_init[gn * HID + d];
    }

  facc4 acc[2][3];
  #pragma unroll
  for (int rt = 0; rt < 2; ++rt)
    #pragma unroll
    for (int g = 0; g < 3; ++g)
      #pragma unroll
      for (int e = 0; e < 4; ++e) acc[rt][g][e] = 0.f;

  #pragma unroll
  for (int k = 0; k < 4; ++k) {
    bfrag8 af[2];
    #pragma unroll
    for (int rt = 0; rt < 2; ++rt) {
      U8 p; p.q = *(const u32x4*)(emb_b + (size_t)idxA[rt] * HID + k * 32 + lgrp * 8);
      p.q.x &= mbA[rt]; p.q.y &= mbA[rt]; p.q.z &= mbA[rt]; p.q.w &= mbA[rt];
      af[rt] = p.b;
    }
    #pragma unroll
    for (int g = 0; g < 3; ++g) {
      bfrag8 bf = *(const bfrag8*)(Wt + (size_t)(g * 128 + w * 16 + lrow) * HID + k * 32 + lgrp * 8);
      acc[0][g] = __builtin_amdgcn_mfma_f32_16x16x32_bf16(af[0], bf, acc[0][g], 0, 0, 0);
      acc[1][g] = __builtin_amdgcn_mfma_f32_16x16x32_bf16(af[1], bf, acc[1][g], 0, 0, 0);
    }
  }

  const float bi = b_iou[d], bo = b_iou[HID + d], bu = b_iou[2 * HID + d];
  #pragma unroll
  for (int rt = 0; rt < 2; ++rt)
    #pragma unroll
    for (int reg = 0; reg < 4; ++reg) {
      int r = r0 + rt * 16 + 4 * lgrp + reg;
      size_t gn = (size_t)(r >> level) * TNODES + (nl - 1) + (r & (nl - 1));
      float iv = acc[rt][0][reg] + bi;
      float ov = acc[rt][1][reg] + bo;
      float uv = acc[rt][2][reg] + bu;
      float cn = fmaf(fast_sigmoid(iv), fast_tanh(uv), ci[rt][reg]);
      float hn = fast_sigmoid(ov) * fast_tanh(cn);
      c_b[(size_t)r * HID + d] = f2b(cn);
      h_b[(size_t)r * HID + d] = f2b(hn);
      h_out[gn * HID + d] = hn;
    }
}

// ---- non-leaf level. 512 thr, wave-private f exchange via LDS columns, zero barriers.
// children of compact row r are compact rows 2r, 2r+1 of the previous level.
template <bool CPB>   // c_prev stored bf16 (only level 13)
__global__ __launch_bounds__(512, 6)
void nonleaf_kernel(int level,
                    const int* __restrict__ wordid, const int* __restrict__ mask,
                    const unsigned short* __restrict__ emb_b,
                    const unsigned short* __restrict__ Wt,
                    const unsigned short* __restrict__ Ut,
                    const unsigned short* __restrict__ Uft,
                    const float* __restrict__ b_iou, const float* __restrict__ U_f_b,
                    const unsigned short* __restrict__ h_prev, const void* __restrict__ c_prev,
                    float* __restrict__ h_out, unsigned short* __restrict__ h_b,
                    float* __restrict__ c_cur) {
  __shared__ __align__(16) unsigned short f_s[64 * 130];
  const int tid = threadIdx.x, lane = tid & 63, w = tid >> 6;
  const int lrow = lane & 15, lgrp = lane >> 4;
  const int R = NTREES << level, nl = 1 << level, R2 = 2 * R;
  int nb = gridDim.x, b = blockIdx.x;
  if ((nb & 7) == 0) { int q = nb >> 3; b = (b & 7) * q + (b >> 3); }
  const int r0 = b * TM;
  const int d = w * 16 + lrow;

  // ---- f-GEMM over the 64 child rows ----
  facc4 accf[4];
  #pragma unroll
  for (int rt = 0; rt < 4; ++rt)
    #pragma unroll
    for (int e = 0; e < 4; ++e) accf[rt][e] = 0.f;
  #pragma unroll
  for (int k = 0; k < 4; ++k) {
    bfrag8 bf = *(const bfrag8*)(Uft + (size_t)(w * 16 + lrow) * HID + k * 32 + lgrp * 8);
    #pragma unroll
    for (int rt = 0; rt < 4; ++rt) {
      int cr = 2 * r0 + rt * 16 + lrow; if (cr >= R2) cr = R2 - 1;
      bfrag8 af = *(const bfrag8*)(h_prev + (size_t)cr * HID + k * 32 + lgrp * 8);
      accf[rt] = __builtin_amdgcn_mfma_f32_16x16x32_bf16(af, bf, accf[rt], 0, 0, 0);
    }
  }
  {
    float fb = U_f_b[d];
    #pragma unroll
    for (int rt = 0; rt < 4; ++rt)
      #pragma unroll
      for (int reg = 0; reg < 4; ++reg) {
        int frow = rt * 16 + 4 * lgrp + reg;
        f_s[frow * 130 + d] = f2b(fast_sigmoid(accf[rt][reg] + fb));
      }
  }

  // ---- c_prev prefetch (hidden under iou GEMM) ----
  float cp0[2][4], cp1[2][4];
  #pragma unroll
  for (int rt = 0; rt < 2; ++rt)
    #pragma unroll
    for (int reg = 0; reg < 4; ++reg) {
      int r = r0 + rt * 16 + 4 * lgrp + reg; if (r >= R) r = R - 1;
      if (CPB) {
        const unsigned short* cp = (const unsigned short*)c_prev;
        cp0[rt][reg] = b2f(cp[(size_t)(2 * r) * HID + d]);
        cp1[rt][reg] = b2f(cp[(size_t)(2 * r + 1) * HID + d]);
      } else {
        const float* cp = (const float*)c_prev;
        cp0[rt][reg] = cp[(size_t)(2 * r) * HID + d];
        cp1[rt][reg] = cp[(size_t)(2 * r + 1) * HID + d];
      }
    }

  // ---- iou GEMM: emb@Wt + ch0@Ut + ch1@Ut (htild folded as two MFMAs) ----
  int idxA[2]; unsigned mbA[2]; int rA[2];
  #pragma unroll
  for (int rt = 0; rt < 2; ++rt) {
    int r = r0 + rt * 16 + lrow; if (r >= R) r = R - 1;
    rA[rt] = r;
    size_t gn = (size_t)(r >> level) * TNODES + (nl - 1) + (r & (nl - 1));
    int mk = mask[gn];
    idxA[rt] = wordid[gn] * mk;
    mbA[rt] = mk ? 0xFFFFFFFFu : 0u;
  }
  facc4 acc[2][3];
  #pragma unroll
  for (int rt = 0; rt < 2; ++rt)
    #pragma unroll
    for (int g = 0; g < 3; ++g)
      #pragma unroll
      for (int e = 0; e < 4; ++e) acc[rt][g][e] = 0.f;

  #pragma unroll
  for (int k = 0; k < 4; ++k) {
    bfrag8 af[2], c0[2], c1[2];
    #pragma unroll
    for (int rt = 0; rt < 2; ++rt) {
      U8 p; p.q = *(const u32x4*)(emb_b + (size_t)idxA[rt] * HID + k * 32 + lgrp * 8);
      p.q.x &= mbA[rt]; p.q.y &= mbA[rt]; p.q.z &= mbA[rt]; p.q.w &= mbA[rt];
      af[rt] = p.b;
      c0[rt] = *(const bfrag8*)(h_prev + (size_t)(2 * rA[rt]) * HID + k * 32 + lgrp * 8);
      c1[rt] = *(const bfrag8*)(h_prev + (size_t)(2 * rA[rt] + 1) * HID + k * 32 + lgrp * 8);
    }
    #pragma unroll
    for (int g = 0; g < 3; ++g) {
      bfrag8 wf = *(const bfrag8*)(Wt + (size_t)(g * 128 + w * 16 + lrow) * HID + k * 32 + lgrp * 8);
      bfrag8 uf = *(const bfrag8*)(Ut + (size_t)(g * 128 + w * 16 + lrow) * HID + k * 32 + lgrp * 8);
      #pragma unroll
      for (int rt = 0; rt < 2; ++rt) {
        acc[rt][g] = __builtin_amdgcn_mfma_f32_16x16x32_bf16(af[rt], wf, acc[rt][g], 0, 0, 0);
        acc[rt][g] = __builtin_amdgcn_mfma_f32_16x16x32_bf16(c0[rt], uf, acc[rt][g], 0, 0, 0);
        acc[rt][g] = __builtin_amdgcn_mfma_f32_16x16x32_bf16(c1[rt], uf, acc[rt][g], 0, 0, 0);
      }
    }
  }

  // ---- LSTM epilogue (f_s columns are wave-private -> no barrier) ----
  const float bi = b_iou[d], bo = b_iou[HID + d], bu = b_iou[2 * HID + d];
  #pragma unroll
  for (int rt = 0; rt < 2; ++rt)
    #pragma unroll
    for (int reg = 0; reg < 4; ++reg) {
      int m = rt * 16 + 4 * lgrp + reg;
      int r = r0 + m;
      if (r >= R) continue;
      int tree = r >> level, j = r & (nl - 1);
      size_t gn = (size_t)tree * TNODES + (nl - 1) + j;
      float iv = acc[rt][0][reg] + bi;
      float ov = acc[rt][1][reg] + bo;
      float uv = acc[rt][2][reg] + bu;
      float cin = b2f(f_s[(2 * m) * 130 + d]) * cp0[rt][reg]
                + b2f(f_s[(2 * m + 1) * 130 + d]) * cp1[rt][reg];
      float cn = fmaf(fast_sigmoid(iv), fast_tanh(uv), cin);
      float hn = fast_sigmoid(ov) * fast_tanh(cn);
      c_cur[(size_t)r * HID + d] = cn;
      h_b[(size_t)r * HID + d] = f2b(hn);
      h_out[gn * HID + d] = hn;
      if (gn == 0) h_out[(size_t)NTREES * TNODES * HID + d] = hn;   // h_all[0] tail
    }
}

extern "C" void kernel_launch(void* const* d_in, const int* in_sizes, int n_in,
                              void* d_out, int out_size, void* d_ws, size_t ws_size,
                              hipStream_t stream) {
  const int*   wordid = (const int*)d_in[0];
  const int*   mask   = (const int*)d_in[1];
  const float* c_init = (const float*)d_in[3];
  const float* emb    = (const float*)d_in[4];
  const float* W_iou  = (const float*)d_in[5];
  const float* U_iou  = (const float*)d_in[6];
  const float* b_iou  = (const float*)d_in[7];
  const float* U_f_w  = (const float*)d_in[8];
  const float* U_f_b  = (const float*)d_in[9];
  float* out = (float*)d_out;

  char* ws = (char*)d_ws;                       // total used: 125,861,888 B (<= proven 134 MB)
  unsigned short* Wt    = (unsigned short*)(ws);                 //  98,304
  unsigned short* Ut    = (unsigned short*)(ws + 98304);         //  98,304
  unsigned short* Uft   = (unsigned short*)(ws + 196608);        //  32,768
  unsigned short* emb_b = (unsigned short*)(ws + 229376);        // 8,192,000
  char* cA = ws + 8421376;     // even-level c: bf16 at leaf (33.5MB), fp32 l<=12 (<=16.8MB)
  char* cB = ws + 41975808;    // odd-level c fp32 (max 33.5MB)
  unsigned short* hA = (unsigned short*)(ws + 75530240);   // even-level h bf16 (max 33.5MB)
  unsigned short* hB = (unsigned short*)(ws + 109084672);  // odd-level h bf16 (max 16.8MB)

  prep_kernel<<<256, 256, 0, stream>>>(W_iou, U_iou, U_f_w, emb, Wt, Ut, Uft, emb_b);

  leaf_kernel<<<(NTREES << (DEPTH - 1)) / TM, 512, 0, stream>>>(
      wordid, mask, c_init, emb_b, Wt, b_iou, out, hA, (unsigned short*)cA);

  for (int l = DEPTH - 2; l >= 0; --l) {
    int R = NTREES << l;
    int nb = (R + TM - 1) / TM;
    float* ccur = (float*)((l & 1) ? cB : cA);
    const void* cprev = (l & 1) ? (const void*)cA : (const void*)cB;
    const unsigned short* hprev = (l & 1) ? hA : hB;
    unsigned short* hcur = (l & 1) ? hB : hA;
    if (l == DEPTH - 2)
      nonleaf_kernel<true><<<nb, 512, 0, stream>>>(l, wordid, mask, emb_b, Wt, Ut, Uft,
                                                   b_iou, U_f_b, hprev, cprev, out, hcur, ccur);
    else
      nonleaf_kernel<false><<<nb, 512, 0, stream>>>(l, wordid, mask, emb_b, Wt, Ut, Uft,
                                                    b_iou, U_f_b, hprev, cprev, out, hcur, ccur);
  }
}